// Round 6
// baseline (230.351 us; speedup 1.0000x reference)
//
#include <hip/hip_runtime.h>
#include <hip/hip_bf16.h>

// Problem constants: B=4, N=4096, C=1024, H=16, d=64
#define BB 4
#define NN 4096
#define CC 1024
#define HH 16
#define MM (BB*NN)          // 16384 token rows
#define EPSF 1e-6f

typedef _Float16 f16x8 __attribute__((ext_vector_type(8)));
typedef float f32x4 __attribute__((ext_vector_type(4)));

__device__ __forceinline__ void gload_lds16(const void* g, void* l) {
    __builtin_amdgcn_global_load_lds(
        (const __attribute__((address_space(1))) void*)g,
        (__attribute__((address_space(3))) void*)l, 16, 0, 0);
}

__device__ __forceinline__ float h2f(short s) {
    return (float)__builtin_bit_cast(_Float16, s);
}

// ---------------------------------------------------------------------------
// fp32 -> fp16, 4 elems/thread
__global__ __launch_bounds__(256)
void tofp16_kernel(const float* __restrict__ src, _Float16* __restrict__ dst, int n4)
{
    int i = blockIdx.x * 256 + threadIdx.x;
    if (i < n4) {
        float4 f = ((const float4*)src)[i];
        short4 pk;
        pk.x = __builtin_bit_cast(short, (_Float16)f.x);
        pk.y = __builtin_bit_cast(short, (_Float16)f.y);
        pk.z = __builtin_bit_cast(short, (_Float16)f.z);
        pk.w = __builtin_bit_cast(short, (_Float16)f.w);
        ((short4*)dst)[i] = pk;
    }
}

// ---------------------------------------------------------------------------
// 256x256-tile fp16 MFMA GEMM, BK=64, 8 waves (2Mx4N), 2 LDS buffers (128KB),
// 4 phases per K-tile (16 MFMA each), stage-2-tiles-ahead, vmcnt(8) counted.
// Race-safety: B-frag reads complete at ph0 lgkmcnt+barrier before B0 stage
// (ph1); A-frag reads complete at ph2 lgkmcnt+barrier before A0/A1/B1 stages
// (ph3). Stages for tile t+2 target buf t&1 (same as being read) — safe by the
// above bracketing. Swizzle: 16B chunk c stored at c^(r&7); reads carry the
// same XOR (kk toggles byte bit 6).
// EPI 0 (QKV): q -> Fq natural + feature map; k -> feature map + transpose to
//              Kt[bh][dk][n]; v -> transpose to Vt[bh][dv][n].
// EPI 1 (proj): +bias -> fp32 out.

#define BARX  do { __builtin_amdgcn_s_barrier(); __builtin_amdgcn_sched_barrier(0); } while(0)
#define LGKM0 do { asm volatile("s_waitcnt lgkmcnt(0)" ::: "memory"); \
                   __builtin_amdgcn_sched_barrier(0); } while(0)
#define VMW8   asm volatile("s_waitcnt vmcnt(8)" ::: "memory")
#define VMW0   asm volatile("s_waitcnt vmcnt(0)" ::: "memory")
#define VMNONE ((void)0)

#define STAGEA(H, CUR, TT) do {                                               \
    _Pragma("unroll")                                                         \
    for (int i_ = 2*(H); i_ < 2*(H)+2; ++i_)                                  \
        gload_lds16(gA[i_] + (TT)*64,                                         \
            (char*)lds + (CUR)*65536 + i_*8192 + tid*16);                     \
} while(0)
#define STAGEB(H, CUR, TT) do {                                               \
    _Pragma("unroll")                                                         \
    for (int i_ = 2*(H); i_ < 2*(H)+2; ++i_)                                  \
        gload_lds16(gB[i_] + (TT)*64,                                         \
            (char*)lds + (CUR)*65536 + 32768 + i_*8192 + tid*16);             \
} while(0)

#define TILE8(CUR, TT, STG, VMACT) do {                                       \
    const char* bc_ = (const char*)lds + (CUR)*65536;                         \
    f16x8 fb_[2][4], fa0_[2][2], fa1_[2][4], fa2_[2][2];                      \
    /* ---- ph0: read all B frags + A m0,m1 ---- */                           \
    _Pragma("unroll") for (int kk_ = 0; kk_ < 2; ++kk_) {                     \
        _Pragma("unroll") for (int n_ = 0; n_ < 4; ++n_)                      \
            fb_[kk_][n_] = *(const f16x8*)(bc_ + boffk[kk_] + n_*2048);       \
        _Pragma("unroll") for (int j_ = 0; j_ < 2; ++j_)                      \
            fa0_[kk_][j_] = *(const f16x8*)(bc_ + aoffk[kk_] + j_*2048);      \
    }                                                                         \
    BARX; LGKM0;                                                              \
    __builtin_amdgcn_s_setprio(1);                                            \
    _Pragma("unroll") for (int kk_ = 0; kk_ < 2; ++kk_)                       \
    _Pragma("unroll") for (int j_ = 0; j_ < 2; ++j_)                          \
    _Pragma("unroll") for (int n_ = 0; n_ < 4; ++n_)                          \
        acc[j_][n_] = __builtin_amdgcn_mfma_f32_16x16x32_f16(                 \
            fa0_[kk_][j_], fb_[kk_][n_], acc[j_][n_], 0, 0, 0);               \
    __builtin_amdgcn_s_setprio(0);                                            \
    BARX;                                                                     \
    /* ---- ph1: read A m2..m5; stage next-next B0 ---- */                    \
    _Pragma("unroll") for (int kk_ = 0; kk_ < 2; ++kk_)                       \
    _Pragma("unroll") for (int j_ = 0; j_ < 4; ++j_)                          \
        fa1_[kk_][j_] = *(const f16x8*)(bc_ + aoffk[kk_] + (2+j_)*2048);      \
    if (STG) STAGEB(0, CUR, (TT)+2);                                          \
    BARX; LGKM0;                                                              \
    __builtin_amdgcn_s_setprio(1);                                            \
    _Pragma("unroll") for (int kk_ = 0; kk_ < 2; ++kk_)                       \
    _Pragma("unroll") for (int j_ = 0; j_ < 2; ++j_)                          \
    _Pragma("unroll") for (int n_ = 0; n_ < 4; ++n_)                          \
        acc[2+j_][n_] = __builtin_amdgcn_mfma_f32_16x16x32_f16(               \
            fa1_[kk_][j_], fb_[kk_][n_], acc[2+j_][n_], 0, 0, 0);             \
    __builtin_amdgcn_s_setprio(0);                                            \
    BARX;                                                                     \
    /* ---- ph2: read A m6,m7; MFMA m4,m5 ---- */                             \
    _Pragma("unroll") for (int kk_ = 0; kk_ < 2; ++kk_)                       \
    _Pragma("unroll") for (int j_ = 0; j_ < 2; ++j_)                          \
        fa2_[kk_][j_] = *(const f16x8*)(bc_ + aoffk[kk_] + (6+j_)*2048);      \
    __builtin_amdgcn_s_setprio(1);                                            \
    _Pragma("unroll") for (int kk_ = 0; kk_ < 2; ++kk_)                       \
    _Pragma("unroll") for (int j_ = 0; j_ < 2; ++j_)                          \
    _Pragma("unroll") for (int n_ = 0; n_ < 4; ++n_)                          \
        acc[4+j_][n_] = __builtin_amdgcn_mfma_f32_16x16x32_f16(               \
            fa1_[kk_][2+j_], fb_[kk_][n_], acc[4+j_][n_], 0, 0, 0);           \
    __builtin_amdgcn_s_setprio(0);                                            \
    LGKM0;                                                                    \
    BARX;                                                                     \
    /* ---- ph3: stage next-next A0,A1,B1; MFMA m6,m7 ---- */                 \
    if (STG) { STAGEA(0, CUR, (TT)+2); STAGEA(1, CUR, (TT)+2);                \
               STAGEB(1, CUR, (TT)+2); }                                      \
    __builtin_amdgcn_s_setprio(1);                                            \
    _Pragma("unroll") for (int kk_ = 0; kk_ < 2; ++kk_)                       \
    _Pragma("unroll") for (int j_ = 0; j_ < 2; ++j_)                          \
    _Pragma("unroll") for (int n_ = 0; n_ < 4; ++n_)                          \
        acc[6+j_][n_] = __builtin_amdgcn_mfma_f32_16x16x32_f16(               \
            fa2_[kk_][j_], fb_[kk_][n_], acc[6+j_][n_], 0, 0, 0);             \
    __builtin_amdgcn_s_setprio(0);                                            \
    VMACT;                                                                    \
    BARX;                                                                     \
} while(0)

template<int EPI>
__global__ __launch_bounds__(512, 2)
void gemm256(const _Float16* __restrict__ A, const _Float16* __restrict__ Bm,
             void* __restrict__ Cout, _Float16* __restrict__ Kt,
             _Float16* __restrict__ Vt, const float* __restrict__ bias,
             const int Ncols, const int gx)
{
    __shared__ _Float16 lds[2 * 32768];   // 128 KB: 2 bufs x (A 32KB + B 32KB)

    const int tid  = threadIdx.x;
    const int lane = tid & 63;
    const int wid  = tid >> 6;           // 0..7
    const int wm   = wid >> 2;           // 0..1 : 128-row half
    const int wn   = wid & 3;            // 0..3 : 64-col quarter

    const int nwg = gridDim.x;
    const int wg  = blockIdx.x;
    const int sw  = (wg & 7) * (nwg >> 3) + (wg >> 3);
    const int by  = sw / gx, bx = sw - by * gx;
    const int brow = by << 8, bcol = bx << 8;

    // stage addressing: load i in 0..3 covers rows i*64..i*64+63 (8KB each)
    const int srow  = tid >> 3;                       // 0..63
    const int sclog = (tid & 7) ^ (srow & 7);         // pre-swizzled source chunk
    const _Float16* gA[4]; const _Float16* gB[4];
#pragma unroll
    for (int i = 0; i < 4; ++i) {
        gA[i] = A  + (size_t)(brow + i * 64 + srow) * 1024 + sclog * 8;
        gB[i] = Bm + (size_t)(bcol + i * 64 + srow) * 1024 + sclog * 8;
    }

    // frag read offsets: row*128 + ((kk*4+q)^(r&7))*16, r&7 == l15&7
    const int l15 = lane & 15, q = lane >> 4, s = l15 & 7;
    const int chunkbase = ((q ^ (s & 3)) << 4) + (((s >> 2) & 1) << 6);
    int aoffk[2], boffk[2];
#pragma unroll
    for (int kk = 0; kk < 2; ++kk) {
        aoffk[kk] = (wm * 128 + l15) * 128 + (chunkbase ^ (kk << 6));
        boffk[kk] = 32768 + (wn * 64 + l15) * 128 + (chunkbase ^ (kk << 6));
    }

    f32x4 acc[8][4] = {};

    // prologue: stage tile0 -> buf0, tile1 -> buf1; wait tile0 (8 left = tile1)
    STAGEA(0, 0, 0); STAGEA(1, 0, 0); STAGEB(0, 0, 0); STAGEB(1, 0, 0);
    STAGEA(0, 1, 1); STAGEA(1, 1, 1); STAGEB(0, 1, 1); STAGEB(1, 1, 1);
    VMW8;
    BARX;

#pragma unroll 1
    for (int tt = 0; tt < 12; tt += 2) {
        TILE8(0, tt,     1, VMW8);
        TILE8(1, tt + 1, 1, VMW8);
    }
    TILE8(0, 12, 1, VMW8);
    TILE8(1, 13, 1, VMW8);
    TILE8(0, 14, 0, VMW0);
    TILE8(1, 15, 0, VMNONE);

    // ---------------- epilogue ----------------
    if (EPI == 0) {
        const int sec = bcol >> 10;          // 0=q, 1=k, 2=v
        const bool feat = (sec < 2);
        if (feat) {
#pragma unroll
            for (int m = 0; m < 8; ++m)
#pragma unroll
                for (int r = 0; r < 4; ++r) {
                    float u[4]; float ssum = 0.f;
#pragma unroll
                    for (int n = 0; n < 4; ++n) {
                        float uu = fmaxf(acc[m][n][r], 0.f) + EPSF;
                        float c = uu * uu * uu;
                        u[n] = c; ssum += c;
                    }
                    ssum += __shfl_xor(ssum, 1, 16);
                    ssum += __shfl_xor(ssum, 2, 16);
                    ssum += __shfl_xor(ssum, 4, 16);
                    ssum += __shfl_xor(ssum, 8, 16);
                    float inv = 1.0f / ssum;
#pragma unroll
                    for (int n = 0; n < 4; ++n) acc[m][n][r] = u[n] * inv;
                }
        }
        if (sec == 0) {
            _Float16* Fo = (_Float16*)Cout;
            const int colb = bcol + wn * 64 + l15;
#pragma unroll
            for (int m = 0; m < 8; ++m) {
                int rb = brow + wm * 128 + m * 16 + q * 4;
#pragma unroll
                for (int r = 0; r < 4; ++r) {
                    size_t base = (size_t)(rb + r) * 1024 + colb;
#pragma unroll
                    for (int n = 0; n < 4; ++n)
                        Fo[base + n * 16] = (_Float16)acc[m][n][r];
                }
            }
        } else {
            _Float16* T = (sec == 1) ? Kt : Vt;
            const int b   = brow >> 12;
            const int hb  = ((bcol & 1023) >> 6) + wn;
            const int bh  = b * 16 + hb;
            const int n0  = (brow & 4095) + wm * 128;
            char* st = (char*)lds + wid * 8704;       // 64 dk x 68 tok fp16
            const int p = l15, q2 = q;
#pragma unroll
            for (int c2 = 0; c2 < 2; ++c2) {
#pragma unroll
                for (int m = 0; m < 4; ++m) {
                    int mm = c2 * 4 + m;
                    int tokc = m * 16 + q2 * 4;
#pragma unroll
                    for (int n = 0; n < 4; ++n) {
                        short4 pk;
                        pk.x = __builtin_bit_cast(short, (_Float16)acc[mm][n][0]);
                        pk.y = __builtin_bit_cast(short, (_Float16)acc[mm][n][1]);
                        pk.z = __builtin_bit_cast(short, (_Float16)acc[mm][n][2]);
                        pk.w = __builtin_bit_cast(short, (_Float16)acc[mm][n][3]);
                        int dk = n * 16 + p;
                        *(short4*)(st + dk * 136 + tokc * 2) = pk;
                    }
                }
#pragma unroll
                for (int it = 0; it < 16; ++it) {
                    int dk = it * 4 + q2;
                    short4 v4 = *(const short4*)(st + dk * 136 + p * 8);
                    *(short4*)(T + ((size_t)(bh * 64 + dk)) * 4096 + n0 + c2 * 64 + p * 4) = v4;
                }
            }
        }
    } else {
        float* Oc = (float*)Cout;
        const int colb = bcol + wn * 64 + l15;
#pragma unroll
        for (int m = 0; m < 8; ++m) {
            int rb = brow + wm * 128 + m * 16 + q * 4;
#pragma unroll
            for (int r = 0; r < 4; ++r) {
                size_t base = (size_t)(rb + r) * Ncols + colb;
#pragma unroll
                for (int n = 0; n < 4; ++n)
                    Oc[base + n * 16] = acc[m][n][r] + bias[colb + n * 16];
            }
        }
    }
}

// ---------------------------------------------------------------------------
// Partial kvT: per (bh, kseg): kvp[kseg][bh][dv][dk] = sum_{n in seg} Vt[dv][n]*Kt[dk][n]
// ksump[kseg][bh][dk] = sum_{n in seg} Kt[dk][n]
__global__ __launch_bounds__(256)
void kv_mfma(const _Float16* __restrict__ Kt, const _Float16* __restrict__ Vt,
             float* __restrict__ kvp, float* __restrict__ ksump)
{
    __shared__ float red[4][64][64];
    __shared__ float ksr[4][64];
    int bx = blockIdx.x;                 // 0..255
    int bh = bx >> 2, kseg = bx & 3;
    int tid = threadIdx.x;
    int w = tid >> 6, lane = tid & 63, p = lane & 15, q = lane >> 4;
    const _Float16* Vb = Vt + (size_t)bh * 64 * 4096;
    const _Float16* Kb = Kt + (size_t)bh * 64 * 4096;
    f32x4 acc[4][4] = {};
    float ksp[4] = {0.f, 0.f, 0.f, 0.f};
    int kbase = kseg * 1024 + w * 256 + q * 8;
#pragma unroll 1
    for (int ks = 0; ks < 8; ++ks) {
        int kb = kbase + ks * 32;
        f16x8 af[4], bf[4];
#pragma unroll
        for (int m = 0; m < 4; ++m)
            af[m] = *(const f16x8*)(Vb + (size_t)(m * 16 + p) * 4096 + kb);
#pragma unroll
        for (int n = 0; n < 4; ++n) {
            bf[n] = *(const f16x8*)(Kb + (size_t)(n * 16 + p) * 4096 + kb);
#pragma unroll
            for (int j = 0; j < 8; ++j) ksp[n] += (float)bf[n][j];
        }
#pragma unroll
        for (int m = 0; m < 4; ++m)
#pragma unroll
            for (int n = 0; n < 4; ++n)
                acc[m][n] = __builtin_amdgcn_mfma_f32_16x16x32_f16(
                    af[m], bf[n], acc[m][n], 0, 0, 0);
    }
#pragma unroll
    for (int n = 0; n < 4; ++n) {
        ksp[n] += __shfl_xor(ksp[n], 16);
        ksp[n] += __shfl_xor(ksp[n], 32);
    }
    if (q == 0)
#pragma unroll
        for (int n = 0; n < 4; ++n) ksr[w][n * 16 + p] = ksp[n];
#pragma unroll
    for (int m = 0; m < 4; ++m)
#pragma unroll
        for (int n = 0; n < 4; ++n)
            *(f32x4*)&red[w][n * 16 + p][m * 16 + q * 4] = acc[m][n];
    __syncthreads();
    int dv = tid & 63, dkb = (tid >> 6) * 16;
    float* ko = kvp + ((size_t)(kseg * 64 + bh)) * 4096;
    f32x4 o[4];
#pragma unroll
    for (int i = 0; i < 16; ++i) {
        float s = red[0][dkb + i][dv] + red[1][dkb + i][dv]
                + red[2][dkb + i][dv] + red[3][dkb + i][dv];
        o[i >> 2][i & 3] = s;
    }
#pragma unroll
    for (int i = 0; i < 4; ++i)
        *(f32x4*)(ko + dv * 64 + dkb + i * 4) = o[i];
    if (tid < 64)
        ksump[(size_t)(kseg * 64 + bh) * 64 + tid] =
            ksr[0][tid] + ksr[1][tid] + ksr[2][tid] + ksr[3][tid];
}

// ---------------------------------------------------------------------------
// Fold 4 k-segment partials: kvT fp16 [bh][dv][dk], ksum f32 [bh][dk]
__global__ __launch_bounds__(256)
void kv_reduce(const float* __restrict__ kvp, const float* __restrict__ ksump,
               _Float16* __restrict__ kvT, float* __restrict__ ksum)
{
    int idx = blockIdx.x * 256 + threadIdx.x;        // 0..262143
    float s = kvp[idx] + kvp[262144 + idx] + kvp[2 * 262144 + idx] + kvp[3 * 262144 + idx];
    kvT[idx] = (_Float16)s;
    if (idx < 4096)
        ksum[idx] = ksump[idx] + ksump[4096 + idx] + ksump[2 * 4096 + idx] + ksump[3 * 4096 + idx];
}

// ---------------------------------------------------------------------------
// Fused attention-out + depthwise conv + residual -> yf (fp16)
// block = (b, h, 256-token chunk); 4 waves x 64 tokens.
__global__ __launch_bounds__(256)
void attn_conv(const _Float16* __restrict__ Fq, const _Float16* __restrict__ kvT,
               const float* __restrict__ ksum, const float* __restrict__ wdwc,
               const float* __restrict__ bdwc, _Float16* __restrict__ yf)
{
    __shared__ _Float16 ybuf[258][68];
    __shared__ float kslds[64];
    int blk = blockIdx.x;
    int b = blk >> 8, h = (blk >> 4) & 15, chunk = blk & 15;
    int bh = b * 16 + h;
    int tid = threadIdx.x, w = tid >> 6, lane = tid & 63, p = lane & 15, q = lane >> 4;
    if (tid < 64) kslds[tid] = ksum[bh * 64 + tid];
    const _Float16* kvb = kvT + (size_t)bh * 4096;
    f16x8 bf[2][4];
#pragma unroll
    for (int kst = 0; kst < 2; ++kst)
#pragma unroll
        for (int n = 0; n < 4; ++n)
            bf[kst][n] = *(const f16x8*)(kvb + (n * 16 + p) * 64 + kst * 32 + q * 8);
    __syncthreads();

    int tok0 = chunk * 256 + w * 64;
    const size_t rowbase = (size_t)(b * 4096 + tok0);
    // z for token row tok0+lane
    f16x8 qr[8];
#pragma unroll
    for (int i = 0; i < 8; ++i)
        qr[i] = *(const f16x8*)(Fq + (rowbase + lane) * 1024 + h * 64 + i * 8);
    float s = 0.f;
#pragma unroll
    for (int i = 0; i < 8; ++i)
#pragma unroll
        for (int j = 0; j < 8; ++j)
            s += (float)qr[i][j] * kslds[i * 8 + j];
    float z = 1.0f / (s + EPSF);

    f32x4 acc[4][4] = {};
#pragma unroll
    for (int kst = 0; kst < 2; ++kst) {
        f16x8 af[4];
#pragma unroll
        for (int m = 0; m < 4; ++m)
            af[m] = *(const f16x8*)(Fq + (rowbase + m * 16 + p) * 1024 + h * 64 + kst * 32 + q * 8);
#pragma unroll
        for (int m = 0; m < 4; ++m)
#pragma unroll
            for (int n = 0; n < 4; ++n)
                acc[m][n] = __builtin_amdgcn_mfma_f32_16x16x32_f16(
                    af[m], bf[kst][n], acc[m][n], 0, 0, 0);
    }
#pragma unroll
    for (int m = 0; m < 4; ++m)
#pragma unroll
        for (int r = 0; r < 4; ++r) {
            float zz = __shfl(z, m * 16 + q * 4 + r);
            int row = 1 + w * 64 + m * 16 + q * 4 + r;
#pragma unroll
            for (int n = 0; n < 4; ++n)
                ybuf[row][n * 16 + p] = (_Float16)(acc[m][n][r] * zz);
        }
    // halo rows (recompute attn for tokens chunk*256-1 and chunk*256+256)
    if (w == 0) {
        float val = 0.f;
        if (chunk > 0) {
            int t = chunk * 256 - 1;
            float sd = 0.f, sz = 0.f;
#pragma unroll
            for (int i = 0; i < 8; ++i) {
                f16x8 qq = *(const f16x8*)(Fq + ((size_t)(b * 4096 + t)) * 1024 + h * 64 + i * 8);
                f16x8 kk = *(const f16x8*)(kvb + lane * 64 + i * 8);
#pragma unroll
                for (int j = 0; j < 8; ++j) {
                    sd += (float)qq[j] * (float)kk[j];
                    sz += (float)qq[j] * kslds[i * 8 + j];
                }
            }
            val = sd / (sz + EPSF);
        }
        ybuf[0][lane] = (_Float16)val;
    }
    if (w == 3) {
        float val = 0.f;
        if (chunk < 15) {
            int t = chunk * 256 + 256;
            float sd = 0.f, sz = 0.f;
#pragma unroll
            for (int i = 0; i < 8; ++i) {
                f16x8 qq = *(const f16x8*)(Fq + ((size_t)(b * 4096 + t)) * 1024 + h * 64 + i * 8);
                f16x8 kk = *(const f16x8*)(kvb + lane * 64 + i * 8);
#pragma unroll
                for (int j = 0; j < 8; ++j) {
                    sd += (float)qq[j] * (float)kk[j];
                    sz += (float)qq[j] * kslds[i * 8 + j];
                }
            }
            val = sd / (sz + EPSF);
        }
        ybuf[257][lane] = (_Float16)val;
    }
    __syncthreads();
    // conv + residual + write
    int dv = lane;
    int c = h * 64 + dv;
    float w0 = wdwc[c * 3 + 0], w1 = wdwc[c * 3 + 1], w2 = wdwc[c * 3 + 2];
    float bb = bdwc[c];
#pragma unroll 4
    for (int it = 0; it < 64; ++it) {
        int tok = it * 4 + w;
        float ym = (float)ybuf[tok][dv];
        float yc = (float)ybuf[tok + 1][dv];
        float yp = (float)ybuf[tok + 2][dv];
        float val = yc + w0 * ym + w1 * yc + w2 * yp + bb;
        yf[((size_t)(b * 4096 + chunk * 256 + tok)) * 1024 + c] = (_Float16)val;
    }
}

// ---------------------------------------------------------------------------
extern "C" void kernel_launch(void* const* d_in, const int* in_sizes, int n_in,
                              void* d_out, int out_size, void* d_ws, size_t ws_size,
                              hipStream_t stream)
{
    const float* x      = (const float*)d_in[0];
    const float* w_qkv  = (const float*)d_in[1];
    const float* w_proj = (const float*)d_in[2];
    const float* b_proj = (const float*)d_in[3];
    const float* w_dwc  = (const float*)d_in[4];
    const float* b_dwc  = (const float*)d_in[5];

    char* p = (char*)d_ws;
    _Float16* xf   = (_Float16*)p;  p += (size_t)MM * CC * 2;         // 33.5 MB
    _Float16* wqf  = (_Float16*)p;  p += (size_t)3 * CC * CC * 2;     // 6.3 MB
    _Float16* wpf  = (_Float16*)p;  p += (size_t)CC * CC * 2;         // 2.1 MB
    _Float16* Fq   = (_Float16*)p;  p += (size_t)MM * CC * 2;         // 33.5 MB
    _Float16* Kt   = (_Float16*)p;  p += (size_t)64 * 64 * NN * 2;    // 33.5 MB
    _Float16* Vt   = (_Float16*)p;  p += (size_t)64 * 64 * NN * 2;    // 33.5 MB
    float*    kvp  = (float*)p;     p += (size_t)4 * 64 * 4096 * 4;   // 4.2 MB
    float*    ksump= (float*)p;     p += (size_t)4 * 64 * 64 * 4;     // 64 KB
    _Float16* kvT  = (_Float16*)p;  p += (size_t)64 * 4096 * 2;       // 0.5 MB
    float*    ksum = (float*)p;     p += (size_t)64 * 64 * 4;         // 16 KB
    _Float16* yf   = (_Float16*)p;  p += (size_t)MM * CC * 2;         // 33.5 MB

    // 1. inputs to fp16
    tofp16_kernel<<<(MM * CC / 4 + 255) / 256, 256, 0, stream>>>(x, xf, MM * CC / 4);
    tofp16_kernel<<<(3 * CC * CC / 4 + 255) / 256, 256, 0, stream>>>(w_qkv, wqf, 3 * CC * CC / 4);
    tofp16_kernel<<<(CC * CC / 4 + 255) / 256, 256, 0, stream>>>(w_proj, wpf, CC * CC / 4);

    // 2. QKV GEMM, feature-map epilogue; q natural, k/v transposed per head
    gemm256<0><<<dim3(12 * 64), 512, 0, stream>>>(
        xf, wqf, (void*)Fq, Kt, Vt, nullptr, 3072, 12);

    // 3. kv partials (MFMA) + fold
    kv_mfma<<<256, 256, 0, stream>>>(Kt, Vt, kvp, ksump);
    kv_reduce<<<1024, 256, 0, stream>>>(kvp, ksump, kvT, ksum);

    // 4. attention output + depthwise conv + residual -> yf
    attn_conv<<<BB * HH * 16, 256, 0, stream>>>(Fq, kvT, ksum, w_dwc, b_dwc, yf);

    // 5. output projection + bias
    gemm256<1><<<dim3(4 * 64), 512, 0, stream>>>(
        yf, wpf, d_out, nullptr, nullptr, b_proj, 1024, 4);
}

// Round 7
// 223.066 us; speedup vs baseline: 1.0327x; 1.0327x over previous
//
#include <hip/hip_runtime.h>
#include <hip/hip_bf16.h>

// Problem constants: B=4, N=4096, C=1024, H=16, d=64
#define BB 4
#define NN 4096
#define CC 1024
#define HH 16
#define MM (BB*NN)          // 16384 token rows
#define EPSF 1e-6f

typedef _Float16 f16x8 __attribute__((ext_vector_type(8)));
typedef float f32x4 __attribute__((ext_vector_type(4)));

__device__ __forceinline__ void gload_lds16(const void* g, void* l) {
    __builtin_amdgcn_global_load_lds(
        (const __attribute__((address_space(1))) void*)g,
        (__attribute__((address_space(3))) void*)l, 16, 0, 0);
}

__device__ __forceinline__ float h2f(short s) {
    return (float)__builtin_bit_cast(_Float16, s);
}

// ---------------------------------------------------------------------------
// fp32 -> fp16, 4 elems/thread
__global__ __launch_bounds__(256)
void tofp16_kernel(const float* __restrict__ src, _Float16* __restrict__ dst, int n4)
{
    int i = blockIdx.x * 256 + threadIdx.x;
    if (i < n4) {
        float4 f = ((const float4*)src)[i];
        short4 pk;
        pk.x = __builtin_bit_cast(short, (_Float16)f.x);
        pk.y = __builtin_bit_cast(short, (_Float16)f.y);
        pk.z = __builtin_bit_cast(short, (_Float16)f.z);
        pk.w = __builtin_bit_cast(short, (_Float16)f.w);
        ((short4*)dst)[i] = pk;
    }
}

// ---------------------------------------------------------------------------
// 256x256-tile fp16 MFMA GEMM, BK=32, 8 waves (2Mx4N), 3 LDS buffers,
// stage-2-ahead with counted vmcnt(4), one barrier per K-tile.  (R5-proven.)
// EPI 0 (QKV): q cols -> Fq natural + feature map; k -> feature map then
//              transposed to Kt[bh][dk][n]; v -> transposed to Vt[bh][dv][n].
// EPI 1 (proj): +bias -> fp32 out.

#define STAGE(BUF, KT) do {                                                          \
    _Pragma("unroll")                                                                \
    for (int j_ = 0; j_ < 2; ++j_) {                                                 \
        gload_lds16(gA[j_] + (KT) * 32, (char*)lds + (BUF) * 32768 + lbase[j_]);     \
        gload_lds16(gB[j_] + (KT) * 32, (char*)lds + (BUF) * 32768 + 16384 + lbase[j_]); \
    } } while (0)

#define TILE(KT, CUR, NXT, DOSTAGE, VMSTR) do {                                      \
    if (DOSTAGE) STAGE(NXT, (KT) + 2);                                               \
    const char* Ab_ = (const char*)lds + (CUR) * 32768 + aoff;                       \
    const char* Bb_ = (const char*)lds + (CUR) * 32768 + 16384 + boff;               \
    f16x8 af_[8], bf_[4];                                                            \
    _Pragma("unroll")                                                                \
    for (int m_ = 0; m_ < 8; ++m_) af_[m_] = *(const f16x8*)(Ab_ + m_ * 1024);       \
    _Pragma("unroll")                                                                \
    for (int n_ = 0; n_ < 4; ++n_) bf_[n_] = *(const f16x8*)(Bb_ + n_ * 1024);       \
    __builtin_amdgcn_s_setprio(1);                                                   \
    _Pragma("unroll")                                                                \
    for (int m_ = 0; m_ < 8; ++m_)                                                   \
    _Pragma("unroll")                                                                \
    for (int n_ = 0; n_ < 4; ++n_)                                                   \
        acc[m_][n_] = __builtin_amdgcn_mfma_f32_16x16x32_f16(af_[m_], bf_[n_],       \
                                                             acc[m_][n_], 0, 0, 0); \
    __builtin_amdgcn_s_setprio(0);                                                   \
    asm volatile("s_waitcnt " VMSTR ::: "memory");                                   \
    __builtin_amdgcn_s_barrier();                                                    \
    __builtin_amdgcn_sched_barrier(0);                                               \
} while (0)

template<int EPI>
__global__ __launch_bounds__(512, 2)
void gemm256(const _Float16* __restrict__ A, const _Float16* __restrict__ Bm,
             void* __restrict__ Cout, _Float16* __restrict__ Kt,
             _Float16* __restrict__ Vt, const float* __restrict__ bias,
             const int Ncols, const int gx)
{
    __shared__ _Float16 lds[3 * 16384];   // 96 KB

    const int tid  = threadIdx.x;
    const int lane = tid & 63;
    const int wid  = tid >> 6;           // 0..7
    const int wm   = wid >> 2;           // 0..1 : 128-row half
    const int wn   = wid & 3;            // 0..3 : 64-col quarter

    const int nwg = gridDim.x;
    const int wg  = blockIdx.x;
    const int sw  = (wg & 7) * (nwg >> 3) + (wg >> 3);
    const int by  = sw / gx, bx = sw - by * gx;
    const int brow = by << 8, bcol = bx << 8;

    const _Float16* gA[2]; const _Float16* gB[2]; int lbase[2];
#pragma unroll
    for (int j = 0; j < 2; ++j) {
        int pos = ((wid * 2 + j) << 10) + (lane << 4);
        int r   = pos >> 6;
        int c8  = ((pos >> 4) & 3) ^ ((r >> 1) & 3);
        gA[j] = A  + (size_t)(brow + r) * 1024 + c8 * 8;
        gB[j] = Bm + (size_t)(bcol + r) * 1024 + c8 * 8;
        lbase[j] = (wid * 2 + j) << 10;
    }

    const int swz  = (((lane >> 4) ^ ((lane >> 1) & 3)) << 4);
    const int aoff = (wm * 128 + (lane & 15)) * 64 + swz;
    const int boff = (wn * 64  + (lane & 15)) * 64 + swz;

    f32x4 acc[8][4] = {};

    STAGE(0, 0);
    STAGE(1, 1);
    asm volatile("s_waitcnt vmcnt(4)" ::: "memory");
    __builtin_amdgcn_s_barrier();
    __builtin_amdgcn_sched_barrier(0);

#pragma unroll 1
    for (int tt = 0; tt < 30; tt += 3) {
        TILE(tt,     0, 2, 1, "vmcnt(4)");
        TILE(tt + 1, 1, 0, 1, "vmcnt(4)");
        TILE(tt + 2, 2, 1, 1, "vmcnt(4)");
    }
    TILE(30, 0, 2, 0, "vmcnt(0)");
    TILE(31, 1, 0, 0, "vmcnt(0)");

    if (EPI == 0) {
        const int sec = bcol >> 10;          // 0=q, 1=k, 2=v
        const bool feat = (sec < 2);
        if (feat) {
#pragma unroll
            for (int m = 0; m < 8; ++m)
#pragma unroll
                for (int r = 0; r < 4; ++r) {
                    float u[4]; float ssum = 0.f;
#pragma unroll
                    for (int n = 0; n < 4; ++n) {
                        float uu = fmaxf(acc[m][n][r], 0.f) + EPSF;
                        float c = uu * uu * uu;
                        u[n] = c; ssum += c;
                    }
                    ssum += __shfl_xor(ssum, 1, 16);
                    ssum += __shfl_xor(ssum, 2, 16);
                    ssum += __shfl_xor(ssum, 4, 16);
                    ssum += __shfl_xor(ssum, 8, 16);
                    float inv = 1.0f / ssum;
#pragma unroll
                    for (int n = 0; n < 4; ++n) acc[m][n][r] = u[n] * inv;
                }
        }
        if (sec == 0) {
            _Float16* Fo = (_Float16*)Cout;
            const int colb = bcol + wn * 64 + (lane & 15);
#pragma unroll
            for (int m = 0; m < 8; ++m) {
                int rb = brow + wm * 128 + m * 16 + (lane >> 4) * 4;
#pragma unroll
                for (int r = 0; r < 4; ++r) {
                    size_t base = (size_t)(rb + r) * 1024 + colb;
#pragma unroll
                    for (int n = 0; n < 4; ++n)
                        Fo[base + n * 16] = (_Float16)acc[m][n][r];
                }
            }
        } else {
            _Float16* T = (sec == 1) ? Kt : Vt;
            const int b   = brow >> 12;
            const int hb  = ((bcol & 1023) >> 6) + wn;
            const int bh  = b * 16 + hb;
            const int n0  = (brow & 4095) + wm * 128;
            char* st = (char*)lds + wid * 8704;       // 64 dk x 68 tok fp16
            const int p = lane & 15, q2 = lane >> 4;
#pragma unroll
            for (int c2 = 0; c2 < 2; ++c2) {
#pragma unroll
                for (int m = 0; m < 4; ++m) {
                    int mm = c2 * 4 + m;
                    int tokc = m * 16 + q2 * 4;
#pragma unroll
                    for (int n = 0; n < 4; ++n) {
                        short4 pk;
                        pk.x = __builtin_bit_cast(short, (_Float16)acc[mm][n][0]);
                        pk.y = __builtin_bit_cast(short, (_Float16)acc[mm][n][1]);
                        pk.z = __builtin_bit_cast(short, (_Float16)acc[mm][n][2]);
                        pk.w = __builtin_bit_cast(short, (_Float16)acc[mm][n][3]);
                        int dk = n * 16 + p;
                        *(short4*)(st + dk * 136 + tokc * 2) = pk;
                    }
                }
#pragma unroll
                for (int it = 0; it < 16; ++it) {
                    int dk = it * 4 + q2;
                    short4 v4 = *(const short4*)(st + dk * 136 + p * 8);
                    *(short4*)(T + ((size_t)(bh * 64 + dk)) * 4096 + n0 + c2 * 64 + p * 4) = v4;
                }
            }
        }
    } else {
        float* Oc = (float*)Cout;
        const int colb = bcol + wn * 64 + (lane & 15);
#pragma unroll
        for (int m = 0; m < 8; ++m) {
            int rb = brow + wm * 128 + m * 16 + (lane >> 4) * 4;
#pragma unroll
            for (int r = 0; r < 4; ++r) {
                size_t base = (size_t)(rb + r) * Ncols + colb;
#pragma unroll
                for (int n = 0; n < 4; ++n)
                    Oc[base + n * 16] = acc[m][n][r] + bias[colb + n * 16];
            }
        }
    }
}

// ---------------------------------------------------------------------------
// Partial kvT: per (bh, kseg): kvp[kseg][bh][dv][dk] = sum_{n in seg} Vt[dv][n]*Kt[dk][n]
// ksump[kseg][bh][dk] = sum_{n in seg} Kt[dk][n]
__global__ __launch_bounds__(256)
void kv_mfma(const _Float16* __restrict__ Kt, const _Float16* __restrict__ Vt,
             float* __restrict__ kvp, float* __restrict__ ksump)
{
    __shared__ float red[4][64][64];
    __shared__ float ksr[4][64];
    int bx = blockIdx.x;                 // 0..255
    int bh = bx >> 2, kseg = bx & 3;
    int tid = threadIdx.x;
    int w = tid >> 6, lane = tid & 63, p = lane & 15, q = lane >> 4;
    const _Float16* Vb = Vt + (size_t)bh * 64 * 4096;
    const _Float16* Kb = Kt + (size_t)bh * 64 * 4096;
    f32x4 acc[4][4] = {};
    float ksp[4] = {0.f, 0.f, 0.f, 0.f};
    int kbase = kseg * 1024 + w * 256 + q * 8;
#pragma unroll 1
    for (int ks = 0; ks < 8; ++ks) {
        int kb = kbase + ks * 32;
        f16x8 af[4], bf[4];
#pragma unroll
        for (int m = 0; m < 4; ++m)
            af[m] = *(const f16x8*)(Vb + (size_t)(m * 16 + p) * 4096 + kb);
#pragma unroll
        for (int n = 0; n < 4; ++n) {
            bf[n] = *(const f16x8*)(Kb + (size_t)(n * 16 + p) * 4096 + kb);
#pragma unroll
            for (int j = 0; j < 8; ++j) ksp[n] += (float)bf[n][j];
        }
#pragma unroll
        for (int m = 0; m < 4; ++m)
#pragma unroll
            for (int n = 0; n < 4; ++n)
                acc[m][n] = __builtin_amdgcn_mfma_f32_16x16x32_f16(
                    af[m], bf[n], acc[m][n], 0, 0, 0);
    }
#pragma unroll
    for (int n = 0; n < 4; ++n) {
        ksp[n] += __shfl_xor(ksp[n], 16);
        ksp[n] += __shfl_xor(ksp[n], 32);
    }
    if (q == 0)
#pragma unroll
        for (int n = 0; n < 4; ++n) ksr[w][n * 16 + p] = ksp[n];
#pragma unroll
    for (int m = 0; m < 4; ++m)
#pragma unroll
        for (int n = 0; n < 4; ++n)
            *(f32x4*)&red[w][n * 16 + p][m * 16 + q * 4] = acc[m][n];
    __syncthreads();
    int dv = tid & 63, dkb = (tid >> 6) * 16;
    float* ko = kvp + ((size_t)(kseg * 64 + bh)) * 4096;
    f32x4 o[4];
#pragma unroll
    for (int i = 0; i < 16; ++i) {
        float s = red[0][dkb + i][dv] + red[1][dkb + i][dv]
                + red[2][dkb + i][dv] + red[3][dkb + i][dv];
        o[i >> 2][i & 3] = s;
    }
#pragma unroll
    for (int i = 0; i < 4; ++i)
        *(f32x4*)(ko + dv * 64 + dkb + i * 4) = o[i];
    if (tid < 64)
        ksump[(size_t)(kseg * 64 + bh) * 64 + tid] =
            ksr[0][tid] + ksr[1][tid] + ksr[2][tid] + ksr[3][tid];
}

// ---------------------------------------------------------------------------
// Fold 4 k-segment partials into extended kvT [bh][80][64] fp16:
// rows 0-63 = kv (dv major), row 64 = ksum, rows 65-79 = 0.
__global__ __launch_bounds__(256)
void kv_reduce(const float* __restrict__ kvp, const float* __restrict__ ksump,
               _Float16* __restrict__ kvT)
{
    int idx = blockIdx.x * 256 + threadIdx.x;        // 0..327679
    int col = idx & 63;
    int t = idx >> 6;                                // 0..5119
    int bh = t / 80;
    int row = t - bh * 80;
    float s = 0.f;
    if (row < 64) {
        int src = bh * 4096 + row * 64 + col;
        s = kvp[src] + kvp[262144 + src] + kvp[2 * 262144 + src] + kvp[3 * 262144 + src];
    } else if (row == 64) {
        int src = bh * 64 + col;
        s = ksump[src] + ksump[4096 + src] + ksump[2 * 4096 + src] + ksump[3 * 4096 + src];
    }
    kvT[idx] = (_Float16)s;
}

// ---------------------------------------------------------------------------
// Fused attention-out + depthwise conv + residual -> yf (fp16)
// block = (b, h, 256-token chunk); 4 waves x 64 tokens.
// z fused via 5th B-fragment (kvT row 64 = ksum): acc[m][4] col 64 = q.ksum.
__global__ __launch_bounds__(256)
void attn_conv(const _Float16* __restrict__ Fq, const _Float16* __restrict__ kvT,
               const float* __restrict__ wdwc, const float* __restrict__ bdwc,
               _Float16* __restrict__ yf)
{
    __shared__ _Float16 ybuf[258][68];
    int blk = blockIdx.x;
    int b = blk >> 8, h = (blk >> 4) & 15, chunk = blk & 15;
    int bh = b * 16 + h;
    int tid = threadIdx.x, w = tid >> 6, lane = tid & 63, p = lane & 15, q = lane >> 4;
    const _Float16* kvb = kvT + (size_t)bh * (80 * 64);
    f16x8 bf[2][5];
#pragma unroll
    for (int kst = 0; kst < 2; ++kst)
#pragma unroll
        for (int n = 0; n < 5; ++n)
            bf[kst][n] = *(const f16x8*)(kvb + (n * 16 + p) * 64 + kst * 32 + q * 8);

    int tok0 = chunk * 256 + w * 64;
    const size_t rowbase = (size_t)(b * 4096 + tok0);

    f32x4 acc[4][5] = {};
#pragma unroll
    for (int kst = 0; kst < 2; ++kst) {
        f16x8 af[4];
#pragma unroll
        for (int m = 0; m < 4; ++m)
            af[m] = *(const f16x8*)(Fq + (rowbase + m * 16 + p) * 1024 + h * 64 + kst * 32 + q * 8);
#pragma unroll
        for (int m = 0; m < 4; ++m)
#pragma unroll
            for (int n = 0; n < 5; ++n)
                acc[m][n] = __builtin_amdgcn_mfma_f32_16x16x32_f16(
                    af[m], bf[kst][n], acc[m][n], 0, 0, 0);
    }
#pragma unroll
    for (int m = 0; m < 4; ++m)
#pragma unroll
        for (int r = 0; r < 4; ++r) {
            float sz = __shfl(acc[m][4][r], lane & 48);   // col 64 = q.ksum for this row
            float zz = 1.0f / (sz + EPSF);
            int row = 1 + w * 64 + m * 16 + q * 4 + r;
#pragma unroll
            for (int n = 0; n < 4; ++n)
                ybuf[row][n * 16 + p] = (_Float16)(acc[m][n][r] * zz);
        }
    // halo rows (recompute attn for tokens chunk*256-1 and chunk*256+256)
    if (w == 0) {
        float val = 0.f;
        if (chunk > 0) {
            int t = chunk * 256 - 1;
            float sd = 0.f, sz = 0.f;
#pragma unroll
            for (int i = 0; i < 8; ++i) {
                f16x8 qq = *(const f16x8*)(Fq + ((size_t)(b * 4096 + t)) * 1024 + h * 64 + i * 8);
                f16x8 kk = *(const f16x8*)(kvb + lane * 64 + i * 8);
                f16x8 ks = *(const f16x8*)(kvb + 64 * 64 + i * 8);
#pragma unroll
                for (int j = 0; j < 8; ++j) {
                    sd += (float)qq[j] * (float)kk[j];
                    sz += (float)qq[j] * (float)ks[j];
                }
            }
            val = sd / (sz + EPSF);
        }
        ybuf[0][lane] = (_Float16)val;
    }
    if (w == 3) {
        float val = 0.f;
        if (chunk < 15) {
            int t = chunk * 256 + 256;
            float sd = 0.f, sz = 0.f;
#pragma unroll
            for (int i = 0; i < 8; ++i) {
                f16x8 qq = *(const f16x8*)(Fq + ((size_t)(b * 4096 + t)) * 1024 + h * 64 + i * 8);
                f16x8 kk = *(const f16x8*)(kvb + lane * 64 + i * 8);
                f16x8 ks = *(const f16x8*)(kvb + 64 * 64 + i * 8);
#pragma unroll
                for (int j = 0; j < 8; ++j) {
                    sd += (float)qq[j] * (float)kk[j];
                    sz += (float)qq[j] * (float)ks[j];
                }
            }
            val = sd / (sz + EPSF);
        }
        ybuf[257][lane] = (_Float16)val;
    }
    __syncthreads();
    // conv + residual + write
    int dv = lane;
    int c = h * 64 + dv;
    float w0 = wdwc[c * 3 + 0], w1 = wdwc[c * 3 + 1], w2 = wdwc[c * 3 + 2];
    float bb = bdwc[c];
#pragma unroll 4
    for (int it = 0; it < 64; ++it) {
        int tok = it * 4 + w;
        float ym = (float)ybuf[tok][dv];
        float yc = (float)ybuf[tok + 1][dv];
        float yp = (float)ybuf[tok + 2][dv];
        float val = yc + w0 * ym + w1 * yc + w2 * yp + bb;
        yf[((size_t)(b * 4096 + chunk * 256 + tok)) * 1024 + c] = (_Float16)val;
    }
}

// ---------------------------------------------------------------------------
extern "C" void kernel_launch(void* const* d_in, const int* in_sizes, int n_in,
                              void* d_out, int out_size, void* d_ws, size_t ws_size,
                              hipStream_t stream)
{
    const float* x      = (const float*)d_in[0];
    const float* w_qkv  = (const float*)d_in[1];
    const float* w_proj = (const float*)d_in[2];
    const float* b_proj = (const float*)d_in[3];
    const float* w_dwc  = (const float*)d_in[4];
    const float* b_dwc  = (const float*)d_in[5];

    char* p = (char*)d_ws;
    _Float16* xf   = (_Float16*)p;  p += (size_t)MM * CC * 2;         // 33.5 MB
    _Float16* wqf  = (_Float16*)p;  p += (size_t)3 * CC * CC * 2;     // 6.3 MB
    _Float16* wpf  = (_Float16*)p;  p += (size_t)CC * CC * 2;         // 2.1 MB
    _Float16* Fq   = (_Float16*)p;  p += (size_t)MM * CC * 2;         // 33.5 MB
    _Float16* Kt   = (_Float16*)p;  p += (size_t)64 * 64 * NN * 2;    // 33.5 MB
    _Float16* Vt   = (_Float16*)p;  p += (size_t)64 * 64 * NN * 2;    // 33.5 MB
    float*    kvp  = (float*)p;     p += (size_t)4 * 64 * 4096 * 4;   // 4.2 MB
    float*    ksump= (float*)p;     p += (size_t)4 * 64 * 64 * 4;     // 64 KB
    _Float16* kvT  = (_Float16*)p;  p += (size_t)64 * 80 * 64 * 2;    // 0.64 MB
    _Float16* yf   = (_Float16*)p;  p += (size_t)MM * CC * 2;         // 33.5 MB

    // 1. inputs to fp16
    tofp16_kernel<<<(MM * CC / 4 + 255) / 256, 256, 0, stream>>>(x, xf, MM * CC / 4);
    tofp16_kernel<<<(3 * CC * CC / 4 + 255) / 256, 256, 0, stream>>>(w_qkv, wqf, 3 * CC * CC / 4);
    tofp16_kernel<<<(CC * CC / 4 + 255) / 256, 256, 0, stream>>>(w_proj, wpf, CC * CC / 4);

    // 2. QKV GEMM, feature-map epilogue; q natural, k/v transposed per head
    gemm256<0><<<dim3(12 * 64), 512, 0, stream>>>(
        xf, wqf, (void*)Fq, Kt, Vt, nullptr, 3072, 12);

    // 3. kv partials (MFMA) + fold into extended kvT (row 64 = ksum)
    kv_mfma<<<256, 256, 0, stream>>>(Kt, Vt, kvp, ksump);
    kv_reduce<<<1280, 256, 0, stream>>>(kvp, ksump, kvT);

    // 4. attention output (z fused via 5th B-frag) + depthwise conv -> yf
    attn_conv<<<BB * HH * 16, 256, 0, stream>>>(Fq, kvT, w_dwc, b_dwc, yf);

    // 5. output projection + bias
    gemm256<1><<<dim3(4 * 64), 512, 0, stream>>>(
        yf, wpf, d_out, nullptr, nullptr, b_proj, 1024, 4);
}

// Round 8
// 218.250 us; speedup vs baseline: 1.0554x; 1.0221x over previous
//
#include <hip/hip_runtime.h>
#include <hip/hip_bf16.h>

// Problem constants: B=4, N=4096, C=1024, H=16, d=64
#define BB 4
#define NN 4096
#define CC 1024
#define HH 16
#define MM (BB*NN)          // 16384 token rows
#define EPSF 1e-6f

typedef _Float16 f16x8 __attribute__((ext_vector_type(8)));
typedef float f32x4 __attribute__((ext_vector_type(4)));

__device__ __forceinline__ void gload_lds16(const void* g, void* l) {
    __builtin_amdgcn_global_load_lds(
        (const __attribute__((address_space(1))) void*)g,
        (__attribute__((address_space(3))) void*)l, 16, 0, 0);
}

// ---------------------------------------------------------------------------
// fused fp32 -> fp16 conversion for x, w_qkv, w_proj (one launch)
// quads: x 4194304, w_qkv 786432, w_proj 262144 ; total 5242880
__global__ __launch_bounds__(256)
void tofp16_all(const float* __restrict__ x, const float* __restrict__ wq,
                const float* __restrict__ wp, _Float16* __restrict__ xf,
                _Float16* __restrict__ wqf, _Float16* __restrict__ wpf)
{
    int i = blockIdx.x * 256 + threadIdx.x;
    const float* src; _Float16* dst; int off;
    if (i < 4194304)      { src = x;  dst = xf;  off = 0; }
    else if (i < 4980736) { src = wq; dst = wqf; off = 4194304; }
    else                  { src = wp; dst = wpf; off = 4980736; }
    int j = i - off;
    float4 f = ((const float4*)src)[j];
    short4 pk;
    pk.x = __builtin_bit_cast(short, (_Float16)f.x);
    pk.y = __builtin_bit_cast(short, (_Float16)f.y);
    pk.z = __builtin_bit_cast(short, (_Float16)f.z);
    pk.w = __builtin_bit_cast(short, (_Float16)f.w);
    ((short4*)dst)[j] = pk;
}

// ---------------------------------------------------------------------------
// 256x256-tile fp16 MFMA GEMM, BK=32, 8 waves (2Mx4N), 3 LDS buffers,
// stage-2-ahead with counted vmcnt(4), one barrier per K-tile.  (R5-proven.)
// EPI 0 (QKV): q cols -> feature map -> Qh[bh][n][dk] (head-major);
//              k -> feature map -> transpose -> Kt[bh][dk][n];
//              v -> transpose -> Vt[bh][dv][n].
// EPI 1 (proj): +bias -> fp32 out.

#define STAGE(BUF, KT) do {                                                          \
    _Pragma("unroll")                                                                \
    for (int j_ = 0; j_ < 2; ++j_) {                                                 \
        gload_lds16(gA[j_] + (KT) * 32, (char*)lds + (BUF) * 32768 + lbase[j_]);     \
        gload_lds16(gB[j_] + (KT) * 32, (char*)lds + (BUF) * 32768 + 16384 + lbase[j_]); \
    } } while (0)

#define TILE(KT, CUR, NXT, DOSTAGE, VMSTR) do {                                      \
    if (DOSTAGE) STAGE(NXT, (KT) + 2);                                               \
    const char* Ab_ = (const char*)lds + (CUR) * 32768 + aoff;                       \
    const char* Bb_ = (const char*)lds + (CUR) * 32768 + 16384 + boff;               \
    f16x8 af_[8], bf_[4];                                                            \
    _Pragma("unroll")                                                                \
    for (int m_ = 0; m_ < 8; ++m_) af_[m_] = *(const f16x8*)(Ab_ + m_ * 1024);       \
    _Pragma("unroll")                                                                \
    for (int n_ = 0; n_ < 4; ++n_) bf_[n_] = *(const f16x8*)(Bb_ + n_ * 1024);       \
    __builtin_amdgcn_s_setprio(1);                                                   \
    _Pragma("unroll")                                                                \
    for (int m_ = 0; m_ < 8; ++m_)                                                   \
    _Pragma("unroll")                                                                \
    for (int n_ = 0; n_ < 4; ++n_)                                                   \
        acc[m_][n_] = __builtin_amdgcn_mfma_f32_16x16x32_f16(af_[m_], bf_[n_],       \
                                                             acc[m_][n_], 0, 0, 0); \
    __builtin_amdgcn_s_setprio(0);                                                   \
    asm volatile("s_waitcnt " VMSTR ::: "memory");                                   \
    __builtin_amdgcn_s_barrier();                                                    \
    __builtin_amdgcn_sched_barrier(0);                                               \
} while (0)

template<int EPI>
__global__ __launch_bounds__(512, 2)
void gemm256(const _Float16* __restrict__ A, const _Float16* __restrict__ Bm,
             void* __restrict__ Cout, _Float16* __restrict__ Kt,
             _Float16* __restrict__ Vt, const float* __restrict__ bias,
             const int Ncols, const int gx)
{
    __shared__ _Float16 lds[3 * 16384];   // 96 KB

    const int tid  = threadIdx.x;
    const int lane = tid & 63;
    const int wid  = tid >> 6;           // 0..7
    const int wm   = wid >> 2;           // 0..1 : 128-row half
    const int wn   = wid & 3;            // 0..3 : 64-col quarter

    const int nwg = gridDim.x;
    const int wg  = blockIdx.x;
    const int sw  = (wg & 7) * (nwg >> 3) + (wg >> 3);
    const int by  = sw / gx, bx = sw - by * gx;
    const int brow = by << 8, bcol = bx << 8;

    const _Float16* gA[2]; const _Float16* gB[2]; int lbase[2];
#pragma unroll
    for (int j = 0; j < 2; ++j) {
        int pos = ((wid * 2 + j) << 10) + (lane << 4);
        int r   = pos >> 6;
        int c8  = ((pos >> 4) & 3) ^ ((r >> 1) & 3);
        gA[j] = A  + (size_t)(brow + r) * 1024 + c8 * 8;
        gB[j] = Bm + (size_t)(bcol + r) * 1024 + c8 * 8;
        lbase[j] = (wid * 2 + j) << 10;
    }

    const int swz  = (((lane >> 4) ^ ((lane >> 1) & 3)) << 4);
    const int aoff = (wm * 128 + (lane & 15)) * 64 + swz;
    const int boff = (wn * 64  + (lane & 15)) * 64 + swz;

    f32x4 acc[8][4] = {};

    STAGE(0, 0);
    STAGE(1, 1);
    asm volatile("s_waitcnt vmcnt(4)" ::: "memory");
    __builtin_amdgcn_s_barrier();
    __builtin_amdgcn_sched_barrier(0);

#pragma unroll 1
    for (int tt = 0; tt < 30; tt += 3) {
        TILE(tt,     0, 2, 1, "vmcnt(4)");
        TILE(tt + 1, 1, 0, 1, "vmcnt(4)");
        TILE(tt + 2, 2, 1, 1, "vmcnt(4)");
    }
    TILE(30, 0, 2, 0, "vmcnt(0)");
    TILE(31, 1, 0, 0, "vmcnt(0)");

    if (EPI == 0) {
        const int sec = bcol >> 10;          // 0=q, 1=k, 2=v
        const bool feat = (sec < 2);
        if (feat) {
#pragma unroll
            for (int m = 0; m < 8; ++m)
#pragma unroll
                for (int r = 0; r < 4; ++r) {
                    float u[4]; float ssum = 0.f;
#pragma unroll
                    for (int n = 0; n < 4; ++n) {
                        float uu = fmaxf(acc[m][n][r], 0.f) + EPSF;
                        float c = uu * uu * uu;
                        u[n] = c; ssum += c;
                    }
                    ssum += __shfl_xor(ssum, 1, 16);
                    ssum += __shfl_xor(ssum, 2, 16);
                    ssum += __shfl_xor(ssum, 4, 16);
                    ssum += __shfl_xor(ssum, 8, 16);
                    float inv = 1.0f / ssum;
#pragma unroll
                    for (int n = 0; n < 4; ++n) acc[m][n][r] = u[n] * inv;
                }
        }
        if (sec == 0) {
            // head-major store: Qh[bh][n][dk]
            _Float16* Qh = (_Float16*)Cout;
            const int b  = brow >> 12;
            const int h  = (bcol >> 6) + wn;
            const size_t qb = (size_t)(b * 16 + h) * 4096;
            const int n0 = (brow & 4095) + wm * 128;
            const int l15 = lane & 15, q = lane >> 4;
#pragma unroll
            for (int m = 0; m < 8; ++m) {
                int nr = n0 + m * 16 + q * 4;
#pragma unroll
                for (int r = 0; r < 4; ++r) {
                    size_t base = (qb + nr + r) * 64 + l15;
#pragma unroll
                    for (int n = 0; n < 4; ++n)
                        Qh[base + n * 16] = (_Float16)acc[m][n][r];
                }
            }
        } else {
            _Float16* T = (sec == 1) ? Kt : Vt;
            const int b   = brow >> 12;
            const int hb  = ((bcol & 1023) >> 6) + wn;
            const int bh  = b * 16 + hb;
            const int n0  = (brow & 4095) + wm * 128;
            char* st = (char*)lds + wid * 8704;       // 64 dk x 68 tok fp16
            const int p = lane & 15, q2 = lane >> 4;
#pragma unroll
            for (int c2 = 0; c2 < 2; ++c2) {
#pragma unroll
                for (int m = 0; m < 4; ++m) {
                    int mm = c2 * 4 + m;
                    int tokc = m * 16 + q2 * 4;
#pragma unroll
                    for (int n = 0; n < 4; ++n) {
                        short4 pk;
                        pk.x = __builtin_bit_cast(short, (_Float16)acc[mm][n][0]);
                        pk.y = __builtin_bit_cast(short, (_Float16)acc[mm][n][1]);
                        pk.z = __builtin_bit_cast(short, (_Float16)acc[mm][n][2]);
                        pk.w = __builtin_bit_cast(short, (_Float16)acc[mm][n][3]);
                        int dk = n * 16 + p;
                        *(short4*)(st + dk * 136 + tokc * 2) = pk;
                    }
                }
#pragma unroll
                for (int it = 0; it < 16; ++it) {
                    int dk = it * 4 + q2;
                    short4 v4 = *(const short4*)(st + dk * 136 + p * 8);
                    *(short4*)(T + ((size_t)(bh * 64 + dk)) * 4096 + n0 + c2 * 64 + p * 4) = v4;
                }
            }
        }
    } else {
        float* Oc = (float*)Cout;
        const int colb = bcol + wn * 64 + (lane & 15);
#pragma unroll
        for (int m = 0; m < 8; ++m) {
            int rb = brow + wm * 128 + m * 16 + (lane >> 4) * 4;
#pragma unroll
            for (int r = 0; r < 4; ++r) {
                size_t base = (size_t)(rb + r) * Ncols + colb;
#pragma unroll
                for (int n = 0; n < 4; ++n)
                    Oc[base + n * 16] = acc[m][n][r] + bias[colb + n * 16];
            }
        }
    }
}

// ---------------------------------------------------------------------------
// Partial kvT: per (bh, kseg): kvp[kseg][bh][dv][dk] = sum_{n in seg} Vt[dv][n]*Kt[dk][n]
// ksump[kseg][bh][dk] = sum_{n in seg} Kt[dk][n]
__global__ __launch_bounds__(256)
void kv_mfma(const _Float16* __restrict__ Kt, const _Float16* __restrict__ Vt,
             float* __restrict__ kvp, float* __restrict__ ksump)
{
    __shared__ float red[4][64][64];
    __shared__ float ksr[4][64];
    int bx = blockIdx.x;                 // 0..255
    int bh = bx >> 2, kseg = bx & 3;
    int tid = threadIdx.x;
    int w = tid >> 6, lane = tid & 63, p = lane & 15, q = lane >> 4;
    const _Float16* Vb = Vt + (size_t)bh * 64 * 4096;
    const _Float16* Kb = Kt + (size_t)bh * 64 * 4096;
    f32x4 acc[4][4] = {};
    float ksp[4] = {0.f, 0.f, 0.f, 0.f};
    int kbase = kseg * 1024 + w * 256 + q * 8;
#pragma unroll 1
    for (int ks = 0; ks < 8; ++ks) {
        int kb = kbase + ks * 32;
        f16x8 af[4], bf[4];
#pragma unroll
        for (int m = 0; m < 4; ++m)
            af[m] = *(const f16x8*)(Vb + (size_t)(m * 16 + p) * 4096 + kb);
#pragma unroll
        for (int n = 0; n < 4; ++n) {
            bf[n] = *(const f16x8*)(Kb + (size_t)(n * 16 + p) * 4096 + kb);
#pragma unroll
            for (int j = 0; j < 8; ++j) ksp[n] += (float)bf[n][j];
        }
#pragma unroll
        for (int m = 0; m < 4; ++m)
#pragma unroll
            for (int n = 0; n < 4; ++n)
                acc[m][n] = __builtin_amdgcn_mfma_f32_16x16x32_f16(
                    af[m], bf[n], acc[m][n], 0, 0, 0);
    }
#pragma unroll
    for (int n = 0; n < 4; ++n) {
        ksp[n] += __shfl_xor(ksp[n], 16);
        ksp[n] += __shfl_xor(ksp[n], 32);
    }
    if (q == 0)
#pragma unroll
        for (int n = 0; n < 4; ++n) ksr[w][n * 16 + p] = ksp[n];
#pragma unroll
    for (int m = 0; m < 4; ++m)
#pragma unroll
        for (int n = 0; n < 4; ++n)
            *(f32x4*)&red[w][n * 16 + p][m * 16 + q * 4] = acc[m][n];
    __syncthreads();
    int dv = tid & 63, dkb = (tid >> 6) * 16;
    float* ko = kvp + ((size_t)(kseg * 64 + bh)) * 4096;
    f32x4 o[4];
#pragma unroll
    for (int i = 0; i < 16; ++i) {
        float s = red[0][dkb + i][dv] + red[1][dkb + i][dv]
                + red[2][dkb + i][dv] + red[3][dkb + i][dv];
        o[i >> 2][i & 3] = s;
    }
#pragma unroll
    for (int i = 0; i < 4; ++i)
        *(f32x4*)(ko + dv * 64 + dkb + i * 4) = o[i];
    if (tid < 64)
        ksump[(size_t)(kseg * 64 + bh) * 64 + tid] =
            ksr[0][tid] + ksr[1][tid] + ksr[2][tid] + ksr[3][tid];
}

// ---------------------------------------------------------------------------
// Fold 4 k-segment partials into extended kvT [bh][80][64] fp16:
// rows 0-63 = kv (dv major), row 64 = ksum, rows 65-79 = 0.
__global__ __launch_bounds__(256)
void kv_reduce(const float* __restrict__ kvp, const float* __restrict__ ksump,
               _Float16* __restrict__ kvT)
{
    int idx = blockIdx.x * 256 + threadIdx.x;        // 0..327679
    int col = idx & 63;
    int t = idx >> 6;                                // 0..5119
    int bh = t / 80;
    int row = t - bh * 80;
    float s = 0.f;
    if (row < 64) {
        int src = bh * 4096 + row * 64 + col;
        s = kvp[src] + kvp[262144 + src] + kvp[2 * 262144 + src] + kvp[3 * 262144 + src];
    } else if (row == 64) {
        int src = bh * 64 + col;
        s = ksump[src] + ksump[4096 + src] + ksump[2 * 4096 + src] + ksump[3 * 4096 + src];
    }
    kvT[idx] = (_Float16)s;
}

// ---------------------------------------------------------------------------
// Fused attention-out + depthwise conv + residual -> yf (fp16)
// block = (b, h, 256-token chunk); 4 waves x 64 tokens. Q head-major.
// z fused via 5th B-fragment (kvT row 64 = ksum): acc[m][4] col 64 = q.ksum.
__global__ __launch_bounds__(256)
void attn_conv(const _Float16* __restrict__ Qh, const _Float16* __restrict__ kvT,
               const float* __restrict__ wdwc, const float* __restrict__ bdwc,
               _Float16* __restrict__ yf)
{
    __shared__ _Float16 ybuf[258][68];
    int blk = blockIdx.x;
    int b = blk >> 8, h = (blk >> 4) & 15, chunk = blk & 15;
    int bh = b * 16 + h;
    int tid = threadIdx.x, w = tid >> 6, lane = tid & 63, p = lane & 15, q = lane >> 4;
    const _Float16* kvb = kvT + (size_t)bh * (80 * 64);
    const _Float16* Qb  = Qh + (size_t)bh * 4096 * 64;
    f16x8 bf[2][5];
#pragma unroll
    for (int kst = 0; kst < 2; ++kst)
#pragma unroll
        for (int n = 0; n < 5; ++n)
            bf[kst][n] = *(const f16x8*)(kvb + (n * 16 + p) * 64 + kst * 32 + q * 8);

    int tok0 = chunk * 256 + w * 64;

    f32x4 acc[4][5] = {};
#pragma unroll
    for (int kst = 0; kst < 2; ++kst) {
        f16x8 af[4];
#pragma unroll
        for (int m = 0; m < 4; ++m)
            af[m] = *(const f16x8*)(Qb + (size_t)(tok0 + m * 16 + p) * 64 + kst * 32 + q * 8);
#pragma unroll
        for (int m = 0; m < 4; ++m)
#pragma unroll
            for (int n = 0; n < 5; ++n)
                acc[m][n] = __builtin_amdgcn_mfma_f32_16x16x32_f16(
                    af[m], bf[kst][n], acc[m][n], 0, 0, 0);
    }
#pragma unroll
    for (int m = 0; m < 4; ++m)
#pragma unroll
        for (int r = 0; r < 4; ++r) {
            float sz = __shfl(acc[m][4][r], lane & 48);   // col 64 = q.ksum for this row
            float zz = 1.0f / (sz + EPSF);
            int row = 1 + w * 64 + m * 16 + q * 4 + r;
#pragma unroll
            for (int n = 0; n < 4; ++n)
                ybuf[row][n * 16 + p] = (_Float16)(acc[m][n][r] * zz);
        }
    // halo rows (recompute attn for tokens chunk*256-1 and chunk*256+256)
    if (w == 0) {
        float val = 0.f;
        if (chunk > 0) {
            int t = chunk * 256 - 1;
            float sd = 0.f, sz = 0.f;
#pragma unroll
            for (int i = 0; i < 8; ++i) {
                f16x8 qq = *(const f16x8*)(Qb + (size_t)t * 64 + i * 8);
                f16x8 kk = *(const f16x8*)(kvb + lane * 64 + i * 8);
                f16x8 ks = *(const f16x8*)(kvb + 64 * 64 + i * 8);
#pragma unroll
                for (int j = 0; j < 8; ++j) {
                    sd += (float)qq[j] * (float)kk[j];
                    sz += (float)qq[j] * (float)ks[j];
                }
            }
            val = sd / (sz + EPSF);
        }
        ybuf[0][lane] = (_Float16)val;
    }
    if (w == 3) {
        float val = 0.f;
        if (chunk < 15) {
            int t = chunk * 256 + 256;
            float sd = 0.f, sz = 0.f;
#pragma unroll
            for (int i = 0; i < 8; ++i) {
                f16x8 qq = *(const f16x8*)(Qb + (size_t)t * 64 + i * 8);
                f16x8 kk = *(const f16x8*)(kvb + lane * 64 + i * 8);
                f16x8 ks = *(const f16x8*)(kvb + 64 * 64 + i * 8);
#pragma unroll
                for (int j = 0; j < 8; ++j) {
                    sd += (float)qq[j] * (float)kk[j];
                    sz += (float)qq[j] * (float)ks[j];
                }
            }
            val = sd / (sz + EPSF);
        }
        ybuf[257][lane] = (_Float16)val;
    }
    __syncthreads();
    // conv + residual + write
    int dv = lane;
    int c = h * 64 + dv;
    float w0 = wdwc[c * 3 + 0], w1 = wdwc[c * 3 + 1], w2 = wdwc[c * 3 + 2];
    float bb = bdwc[c];
#pragma unroll 4
    for (int it = 0; it < 64; ++it) {
        int tok = it * 4 + w;
        float ym = (float)ybuf[tok][dv];
        float yc = (float)ybuf[tok + 1][dv];
        float yp = (float)ybuf[tok + 2][dv];
        float val = yc + w0 * ym + w1 * yc + w2 * yp + bb;
        yf[((size_t)(b * 4096 + chunk * 256 + tok)) * 1024 + c] = (_Float16)val;
    }
}

// ---------------------------------------------------------------------------
extern "C" void kernel_launch(void* const* d_in, const int* in_sizes, int n_in,
                              void* d_out, int out_size, void* d_ws, size_t ws_size,
                              hipStream_t stream)
{
    const float* x      = (const float*)d_in[0];
    const float* w_qkv  = (const float*)d_in[1];
    const float* w_proj = (const float*)d_in[2];
    const float* b_proj = (const float*)d_in[3];
    const float* w_dwc  = (const float*)d_in[4];
    const float* b_dwc  = (const float*)d_in[5];

    char* p = (char*)d_ws;
    _Float16* xf   = (_Float16*)p;  p += (size_t)MM * CC * 2;         // 33.5 MB
    _Float16* wqf  = (_Float16*)p;  p += (size_t)3 * CC * CC * 2;     // 6.3 MB
    _Float16* wpf  = (_Float16*)p;  p += (size_t)CC * CC * 2;         // 2.1 MB
    _Float16* Qh   = (_Float16*)p;  p += (size_t)MM * CC * 2;         // 33.5 MB
    _Float16* Kt   = (_Float16*)p;  p += (size_t)64 * 64 * NN * 2;    // 33.5 MB
    _Float16* Vt   = (_Float16*)p;  p += (size_t)64 * 64 * NN * 2;    // 33.5 MB
    float*    kvp  = (float*)p;     p += (size_t)4 * 64 * 4096 * 4;   // 4.2 MB
    float*    ksump= (float*)p;     p += (size_t)4 * 64 * 64 * 4;     // 64 KB
    _Float16* kvT  = (_Float16*)p;  p += (size_t)64 * 80 * 64 * 2;    // 0.64 MB
    _Float16* yf   = (_Float16*)p;  p += (size_t)MM * CC * 2;         // 33.5 MB

    // 1. inputs to fp16 (single fused launch)
    tofp16_all<<<20480, 256, 0, stream>>>(x, w_qkv, w_proj, xf, wqf, wpf);

    // 2. QKV GEMM, feature-map epilogue; q head-major, k/v transposed per head
    gemm256<0><<<dim3(12 * 64), 512, 0, stream>>>(
        xf, wqf, (void*)Qh, Kt, Vt, nullptr, 3072, 12);

    // 3. kv partials (MFMA) + fold into extended kvT (row 64 = ksum)
    kv_mfma<<<256, 256, 0, stream>>>(Kt, Vt, kvp, ksump);
    kv_reduce<<<1280, 256, 0, stream>>>(kvp, ksump, kvT);

    // 4. attention output (z fused via 5th B-frag) + depthwise conv -> yf
    attn_conv<<<BB * HH * 16, 256, 0, stream>>>(Qh, kvT, w_dwc, b_dwc, yf);

    // 5. output projection + bias
    gemm256<1><<<dim3(4 * 64), 512, 0, stream>>>(
        yf, wpf, d_out, nullptr, nullptr, b_proj, 1024, 4);
}